// Round 25
// baseline (169.910 us; speedup 1.0000x reference)
//
#include <hip/hip_runtime.h>
#include <math.h>

#define EPS 1e-5f

typedef float f32x16 __attribute__((ext_vector_type(16)));
typedef short short8 __attribute__((ext_vector_type(8)));

union U4S8 { uint4 u; short8 s; };

__device__ __forceinline__ float wave_sum64(float v) {
#pragma unroll
  for (int off = 32; off >= 1; off >>= 1) v += __shfl_xor(v, off, 64);
  return v;
}

__device__ __forceinline__ unsigned int bf16rne(float f) {
  unsigned int u = __float_as_uint(f);
  return (u + 0x7fffu + ((u >> 16) & 1u)) >> 16;
}
__device__ __forceinline__ float blo(unsigned int u) {
  return __uint_as_float(u << 16);
}
__device__ __forceinline__ float bhi(unsigned int u) {
  return __uint_as_float(u & 0xffff0000u);
}
__device__ __forceinline__ unsigned int cvt_pk_bf16(float lo, float hi) {
  unsigned int r;
  asm("v_cvt_pk_bf16_f32 %0, %1, %2" : "=v"(r) : "v"(lo), "v"(hi));
  return r;
}

// K0: embed + qkv projection for layer 0 + weight prep, fused (round-24).
__global__ __launch_bounds__(192) void k_qkv0(
    const float* __restrict__ weather, const float* __restrict__ coords,
    const float* __restrict__ W_emb, const float* __restrict__ b_emb,
    const float* __restrict__ Wq, const float* __restrict__ bq,
    const float* __restrict__ gran, const int* __restrict__ tidx,
    const float* __restrict__ Wo_f, const float* __restrict__ W1_f,
    const float* __restrict__ W2_f,
    float* __restrict__ x, unsigned int* __restrict__ qb,
    unsigned int* __restrict__ kbuf, unsigned short* __restrict__ vt,
    unsigned int* __restrict__ wbo, unsigned int* __restrict__ w1b,
    unsigned int* __restrict__ w2b, unsigned int* __restrict__ wqb) {
  int t = threadIdx.x;
  int row0 = blockIdx.x << 3;
  __shared__ float wrow[8][32];
  __shared__ float xs[8][64];
  for (int i = t; i < 256; i += 192) {
    int r = i >> 5, c2 = i & 31;
    if (c2 < 31) wrow[r][c2] = weather[(size_t)(row0 + r) * 31 + c2];
  }
  __syncthreads();
  int b = row0 >> 10;
  float lat = coords[b * 2 + 0] * 0.017453292519943295f;
  float lon = coords[b * 2 + 1] * 0.017453292519943295f;
  for (int idx = t; idx < 512; idx += 192) {
    int r = idx >> 6, e = idx & 63;
    int s = (row0 + r) & 1023;
    float acc = b_emb[e];
#pragma unroll
    for (int i = 0; i < 31; ++i) acc = fmaf(wrow[r][i], W_emb[i * 64 + e], acc);
    int g = e >> 2, rem = e & 3;
    float div = __expf(-0.5756462732485115f * (float)g);
    float pe;
    if (rem == 0)      pe = sinf((float)s * div);
    else if (rem == 1) pe = cosf((float)s * div);
    else if (rem == 2) pe = sinf(lat * div);
    else               pe = cosf(lon * div);
    float xv = acc + pe;
    xs[r][e] = xv;
    x[(size_t)(row0 + r) * 64 + e] = xv;
  }
  __syncthreads();
  float acc[8];
  float bias = bq[t];
#pragma unroll
  for (int r = 0; r < 8; ++r) acc[r] = bias;
#pragma unroll 4
  for (int k4 = 0; k4 < 16; ++k4) {
    float4 xv[8];
#pragma unroll
    for (int r = 0; r < 8; ++r) xv[r] = *(const float4*)(&xs[r][4 * k4]);
    float w0 = Wq[(4 * k4 + 0) * 192 + t];
    float w1 = Wq[(4 * k4 + 1) * 192 + t];
    float w2 = Wq[(4 * k4 + 2) * 192 + t];
    float w3 = Wq[(4 * k4 + 3) * 192 + t];
#pragma unroll
    for (int r = 0; r < 8; ++r) {
      acc[r] = fmaf(xv[r].x, w0, acc[r]);
      acc[r] = fmaf(xv[r].y, w1, acc[r]);
      acc[r] = fmaf(xv[r].z, w2, acc[r]);
      acc[r] = fmaf(xv[r].w, w3, acc[r]);
    }
  }
  int cq = t & 63;
  int hh = cq >> 3, hd = t & 7;
  int shi = (row0 & 1023) >> 3;
  int s2 = (b << 7) | shi;
  const float scl = 0.35355339059327373f;
#pragma unroll
  for (int r = 0; r < 8; ++r) {
    float o = acc[r];
    if (t < 128) o += gran[tidx[2 * r + 1] * 64 + cq];
    int bh = (r << 3) | hh;
    if (t < 64) {
      o *= scl;
      float nb = __shfl_down(o, 1, 64);
      if ((hd & 1) == 0)
        qb[((((size_t)bh << 10) | s2) << 2) + (hd >> 1)] =
            bf16rne(o) | (bf16rne(nb) << 16);
    } else if (t < 128) {
      float nb = __shfl_down(o, 1, 64);
      if ((hd & 1) == 0)
        kbuf[((((size_t)bh << 10) | s2) << 2) + (hd >> 1)] =
            bf16rne(o) | (bf16rne(nb) << 16);
    } else {
      vt[((size_t)bh << 13) + (hd << 10) + s2] = (unsigned short)bf16rne(o);
    }
  }
  // ---- weight-prep phase (one packed pair per thread, gid < 67584)
  int gid = blockIdx.x * 192 + t;
  if (gid < 6144) {
    int ll = gid >> 11, rem = gid & 2047, p = rem >> 6, c2 = rem & 63;
    const float* s = Wo_f + ll * 4096;
    wbo[gid] = bf16rne(s[(2 * p) * 64 + c2]) |
               (bf16rne(s[(2 * p + 1) * 64 + c2]) << 16);
  } else if (gid < 30720) {
    int i = gid - 6144;
    int ll = i / 8192, rem = i & 8191, p = rem >> 8, c2 = rem & 255;
    const float* s = W1_f + (size_t)ll * 16384;
    w1b[i] = bf16rne(s[(2 * p) * 256 + c2]) |
             (bf16rne(s[(2 * p + 1) * 256 + c2]) << 16);
  } else if (gid < 55296) {
    int i = gid - 30720;
    int ll = i / 8192, rem = i & 8191, p = rem >> 6, c2 = rem & 63;
    const float* s = W2_f + (size_t)ll * 16384;
    w2b[i] = bf16rne(s[(2 * p) * 64 + c2]) |
             (bf16rne(s[(2 * p + 1) * 64 + c2]) << 16);
  } else if (gid < 67584) {
    int i = gid - 55296;
    int ll = i / 6144, rem = i % 6144, p = rem / 192, c2 = rem % 192;
    const float* s = Wq + (size_t)(ll + 1) * 12288;
    wqb[i] = bf16rne(s[(2 * p) * 192 + c2]) |
             (bf16rne(s[(2 * p + 1) * 192 + c2]) << 16);
  }
}

// K3 v3: MFMA flash attention, split-K x4 in-block (round-24 kernel).
__global__ __launch_bounds__(512, 2) void k_attn(
    const unsigned int* __restrict__ qb, const unsigned int* __restrict__ kbuf,
    const unsigned short* __restrict__ vt, float* __restrict__ ao) {
  int bh = blockIdx.x >> 4, chunk = blockIdx.x & 15;
  int slo = bh >> 3, h = bh & 7;
  int t = threadIdx.x;
  int l = t & 63, w = t >> 6;
  int grp = w >> 2, kh = w & 3;   // 2 q-groups x 4 key-splits
  int lq = l & 31, g = l >> 5;
  bool kl = (l < 32);
  bool vl = (lq < 8);
  int q = (chunk << 6) + (grp << 5) + lq;

  U4S8 qf;
  qf.u = make_uint4(0, 0, 0, 0);
  if (kl) qf.u = *(const uint4*)(qb + ((((size_t)bh << 10) + q) << 2));

  const uint4* kp = (const uint4*)(kbuf + ((size_t)bh << 12));
  const unsigned short* vp = vt + ((size_t)bh << 13);

  f32x16 O, Z;
#pragma unroll
  for (int i = 0; i < 16; ++i) { O[i] = 0.f; Z[i] = 0.f; }
  float m = -1e30f, ls = 0.f;

  int kb0 = kh << 3;
  for (int kblk = kb0; kblk < kb0 + 8; ++kblk) {
    U4S8 af;
    af.u = make_uint4(0, 0, 0, 0);
    if (kl) af.u = kp[(kblk << 5) + lq];
    f32x16 S = __builtin_amdgcn_mfma_f32_32x32x16_bf16(af.s, qf.s, Z, 0, 0, 0);

    float mx = S[0];
#pragma unroll
    for (int i = 1; i < 16; ++i) mx = fmaxf(mx, S[i]);
    mx = fmaxf(mx, __shfl_xor(mx, 32, 64));
    if (mx > m + 8.f) {
      float esc = __expf(m - mx);
      ls *= esc;
      O *= esc;
      m = mx;
    }
    float p[16];
#pragma unroll
    for (int i = 0; i < 16; ++i) p[i] = __expf(S[i] - m);
    float s01 = (p[0] + p[1]) + (p[2] + p[3]);
    float s23 = (p[4] + p[5]) + (p[6] + p[7]);
    float s45 = (p[8] + p[9]) + (p[10] + p[11]);
    float s67 = (p[12] + p[13]) + (p[14] + p[15]);
    ls += (s01 + s23) + (s45 + s67);

    unsigned va = cvt_pk_bf16(p[0], p[1]),  vb = cvt_pk_bf16(p[2], p[3]);
    unsigned vc = cvt_pk_bf16(p[4], p[5]),  vd = cvt_pk_bf16(p[6], p[7]);
    unsigned ve = cvt_pk_bf16(p[8], p[9]),  vf = cvt_pk_bf16(p[10], p[11]);
    unsigned vg = cvt_pk_bf16(p[12], p[13]), vh = cvt_pk_bf16(p[14], p[15]);
    unsigned sa = __shfl_xor((int)va, 32, 64), sb = __shfl_xor((int)vb, 32, 64);
    unsigned sc = __shfl_xor((int)vc, 32, 64), sd = __shfl_xor((int)vd, 32, 64);
    unsigned se = __shfl_xor((int)ve, 32, 64), sf = __shfl_xor((int)vf, 32, 64);
    unsigned sg = __shfl_xor((int)vg, 32, 64), sh = __shfl_xor((int)vh, 32, 64);
    U4S8 b1, b2;
    b1.u.x = kl ? va : sc;  b1.u.y = kl ? vb : sd;
    b1.u.z = kl ? sa : vc;  b1.u.w = kl ? sb : vd;
    b2.u.x = kl ? ve : sg;  b2.u.y = kl ? vf : sh;
    b2.u.z = kl ? se : vg;  b2.u.w = kl ? sf : vh;

    U4S8 v1, v2;
    v1.u = make_uint4(0, 0, 0, 0);
    v2.u = make_uint4(0, 0, 0, 0);
    if (vl) {
      const unsigned short* vb8 = vp + (lq << 10) + (kblk << 5) + (g << 3);
      v1.u = *(const uint4*)vb8;
      v2.u = *(const uint4*)(vb8 + 16);
    }
    O = __builtin_amdgcn_mfma_f32_32x32x16_bf16(v1.s, b1.s, O, 0, 0, 0);
    O = __builtin_amdgcn_mfma_f32_32x32x16_bf16(v2.s, b2.s, O, 0, 0, 0);
  }

  ls += __shfl_xor(ls, 32, 64);  // pair partials share m -> plain add

  // 4-way cross-wave merge (12KB LDS); wave kh==0 merges and writes.
  __shared__ float pm[2][4][64], pl[2][4][64];
  __shared__ float po[2][4][64][4];
  pm[grp][kh][l] = m;
  pl[grp][kh][l] = ls;
  *(float4*)(&po[grp][kh][l][0]) = make_float4(O[0], O[1], O[2], O[3]);
  __syncthreads();
  if (kh == 0) {
    float M = m;
#pragma unroll
    for (int j = 1; j < 4; ++j) M = fmaxf(M, pm[grp][j][l]);
    float w0 = __expf(m - M);
    float L = ls * w0;
    float o0 = O[0] * w0, o1 = O[1] * w0, o2 = O[2] * w0, o3 = O[3] * w0;
#pragma unroll
    for (int j = 1; j < 4; ++j) {
      float wj = __expf(pm[grp][j][l] - M);
      L = fmaf(pl[grp][j][l], wj, L);
      float4 oj = *(const float4*)(&po[grp][j][l][0]);
      o0 = fmaf(oj.x, wj, o0);
      o1 = fmaf(oj.y, wj, o1);
      o2 = fmaf(oj.z, wj, o2);
      o3 = fmaf(oj.w, wj, o3);
    }
    float inv = 1.0f / L;
    int bq2 = q >> 7, sq = ((q & 127) << 3) | slo;
    float* op = ao + (((size_t)((bq2 << 10) | sq)) << 6) + (h << 3) + (g << 2);
    *(float4*)op = make_float4(o0 * inv, o1 * inv, o2 * inv, o3 * inv);
  }
}

// K4 v12: fused layer, 1 ROW PER WAVE (4 rows/block, grid 2048).
// Round-24 analysis: at 2 rows/wave the kernel was GRID-limited to 4
// blocks/CU (Occ 32%); it is latency- not BW-bound (R23: bf16 weights
// ~no change), so trading 2x weight re-reads for 2x residency is correct.
// Now 2048 blocks = 8 blocks/CU = 32 waves/CU by threads. LDS ~5KB.
// (256,4) cap; natural liveness ~45 (R19's 2-row body was 52) -> the
// allocator should land <=64 naturally, allowing 8 waves/SIMD.
template <bool EMIT, bool HEAD>
__global__ __launch_bounds__(256, 4) void k_fused(
    const float* x_in, const float* __restrict__ ao,
    const unsigned int* __restrict__ Wo, const float* __restrict__ bo,
    const float* __restrict__ g1, const float* __restrict__ be1,
    const unsigned int* __restrict__ W1, const float* __restrict__ b1,
    const unsigned int* __restrict__ W2, const float* __restrict__ b2,
    const float* __restrict__ g2, const float* __restrict__ be2,
    const unsigned int* __restrict__ Wq, const float* __restrict__ bq,
    const float* __restrict__ gran, const int* __restrict__ tidx,
    unsigned int* __restrict__ qbo, unsigned int* __restrict__ kbo,
    unsigned short* __restrict__ vto,
    const float* __restrict__ Wfc, const float* __restrict__ bfc,
    float* __restrict__ outp, float* __restrict__ x_out) {
  int t = threadIdx.x, w = t >> 6, c = t & 63;
  int row_base = blockIdx.x << 2;   // 4 rows per block
  int row = row_base + w;           // this wave's row
  __shared__ float aos[4][64];      // ao -> x1 -> x_out staging
  __shared__ float h1s[4][256];
  aos[w][c] = ao[(size_t)row * 64 + c];
  float xin = x_in[(size_t)row * 64 + c];
  // ---- proj + residual + LN1 (wave-private row; no barrier)
  float acc = bo[c];
#pragma unroll 4
  for (int k4 = 0; k4 < 16; ++k4) {
    unsigned a = Wo[(2 * k4) * 64 + c], b = Wo[(2 * k4 + 1) * 64 + c];
    float4 av = *(const float4*)(&aos[w][4 * k4]);
    acc = fmaf(av.x, blo(a), acc);
    acc = fmaf(av.y, bhi(a), acc);
    acc = fmaf(av.z, blo(b), acc);
    acc = fmaf(av.w, bhi(b), acc);
  }
  float y = acc + xin;
  float s1 = wave_sum64(y), s2v = wave_sum64(y * y);
  float mean = s1 * 0.015625f, var = s2v * 0.015625f - mean * mean;
  float x1v = (y - mean) * rsqrtf(var + EPS) * g1[c] + be1[c];
  aos[w][c] = x1v;  // aos dead after proj; reuse for x1
  // ---- ffn1 (x1 from aos, wave-private; W1 bf16 pairs)
  float4 h = *(const float4*)(b1 + 4 * c);
#pragma unroll 4
  for (int k4 = 0; k4 < 16; ++k4) {
    uint4 A = *(const uint4*)(W1 + (2 * k4) * 256 + 4 * c);
    uint4 B = *(const uint4*)(W1 + (2 * k4 + 1) * 256 + 4 * c);
    float4 xv = *(const float4*)(&aos[w][4 * k4]);
    h.x = fmaf(xv.x, blo(A.x), h.x); h.y = fmaf(xv.x, blo(A.y), h.y);
    h.z = fmaf(xv.x, blo(A.z), h.z); h.w = fmaf(xv.x, blo(A.w), h.w);
    h.x = fmaf(xv.y, bhi(A.x), h.x); h.y = fmaf(xv.y, bhi(A.y), h.y);
    h.z = fmaf(xv.y, bhi(A.z), h.z); h.w = fmaf(xv.y, bhi(A.w), h.w);
    h.x = fmaf(xv.z, blo(B.x), h.x); h.y = fmaf(xv.z, blo(B.y), h.y);
    h.z = fmaf(xv.z, blo(B.z), h.z); h.w = fmaf(xv.z, blo(B.w), h.w);
    h.x = fmaf(xv.w, bhi(B.x), h.x); h.y = fmaf(xv.w, bhi(B.y), h.y);
    h.z = fmaf(xv.w, bhi(B.z), h.z); h.w = fmaf(xv.w, bhi(B.w), h.w);
  }
  h.x = fmaxf(h.x, 0.f); h.y = fmaxf(h.y, 0.f);
  h.z = fmaxf(h.z, 0.f); h.w = fmaxf(h.w, 0.f);
  *(float4*)(&h1s[w][4 * c]) = h;
  // ---- ffn2 (h1 wave-private from LDS; W2 bf16 pairs) + LN2
  float acc2 = b2[c];
#pragma unroll 4
  for (int k4 = 0; k4 < 64; ++k4) {
    unsigned a = W2[(2 * k4) * 64 + c], b = W2[(2 * k4 + 1) * 64 + c];
    float4 hv = *(const float4*)(&h1s[w][4 * k4]);
    acc2 = fmaf(hv.x, blo(a), acc2);
    acc2 = fmaf(hv.y, bhi(a), acc2);
    acc2 = fmaf(hv.z, blo(b), acc2);
    acc2 = fmaf(hv.w, bhi(b), acc2);
  }
  float y2 = acc2 + x1v;
  float t1 = wave_sum64(y2), t2 = wave_sum64(y2 * y2);
  float mean2 = t1 * 0.015625f, var2 = t2 * 0.015625f - mean2 * mean2;
  float xo = (y2 - mean2) * rsqrtf(var2 + EPS) * g2[c] + be2[c];
  if (!HEAD) x_out[(size_t)row * 64 + c] = xo;
  aos[w][c] = xo;  // stage for qkv/head phase (x1 dead now)
  if (EMIT) {
    __syncthreads();  // all 4 x_out rows visible block-wide
    if (t < 192) {
      float qa[4];
      float bias = bq[t];
#pragma unroll
      for (int r = 0; r < 4; ++r) qa[r] = bias;
#pragma unroll 4
      for (int k4 = 0; k4 < 16; ++k4) {
        unsigned a = Wq[(2 * k4) * 192 + t], b = Wq[(2 * k4 + 1) * 192 + t];
        float w0 = blo(a), w1 = bhi(a), w2v = blo(b), w3 = bhi(b);
#pragma unroll
        for (int r = 0; r < 4; ++r) {
          float4 av = *(const float4*)(&aos[r][4 * k4]);
          qa[r] = fmaf(av.x, w0, qa[r]);
          qa[r] = fmaf(av.y, w1, qa[r]);
          qa[r] = fmaf(av.z, w2v, qa[r]);
          qa[r] = fmaf(av.w, w3, qa[r]);
        }
      }
      int cq = t & 63, hh = cq >> 3, hd = t & 7;
      int bb = row_base >> 10;
      int s2 = (bb << 7) | ((row_base & 1023) >> 3);  // same for all 4 rows
      const float scl = 0.35355339059327373f;
#pragma unroll
      for (int r = 0; r < 4; ++r) {
        int rr = (row_base + r) & 7;
        float o = qa[r];
        if (t < 128) o += gran[tidx[2 * rr + 1] * 64 + cq];
        int bh = (rr << 3) | hh;
        size_t base = ((size_t)(bh << 10)) | s2;
        if (t < 64) {
          o *= scl;
          float nb = __shfl_down(o, 1, 64);
          if ((hd & 1) == 0)
            qbo[(base << 2) + (hd >> 1)] = bf16rne(o) | (bf16rne(nb) << 16);
        } else if (t < 128) {
          float nb = __shfl_down(o, 1, 64);
          if ((hd & 1) == 0)
            kbo[(base << 2) + (hd >> 1)] = bf16rne(o) | (bf16rne(nb) << 16);
        } else {
          vto[((size_t)bh << 13) + (hd << 10) + s2] = (unsigned short)bf16rne(o);
        }
      }
    }
  }
  if (HEAD) {
    __syncthreads();  // all 4 x_out rows visible block-wide
    int r = t >> 6, o = t & 63;  // 4 rows x 64 slots; o>=31 idle
    if (o < 31) {
      float acc3 = bfc[o];
#pragma unroll 8
      for (int i = 0; i < 64; ++i)
        acc3 = fmaf(aos[r][i], Wfc[i * 31 + o], acc3);
      outp[(size_t)(row_base + r) * 31 + o] = acc3;
    }
  }
}

extern "C" void kernel_launch(void* const* d_in, const int* in_sizes, int n_in,
                              void* d_out, int out_size, void* d_ws, size_t ws_size,
                              hipStream_t stream) {
  const float* weather = (const float*)d_in[0];
  const float* coords  = (const float*)d_in[1];
  const int*   tidx    = (const int*)d_in[2];
  const float* W_emb   = (const float*)d_in[3];
  const float* b_emb   = (const float*)d_in[4];
  const float* W_qkv   = (const float*)d_in[5];
  const float* b_qkv   = (const float*)d_in[6];
  const float* W_out   = (const float*)d_in[7];
  const float* b_out   = (const float*)d_in[8];
  const float* gran    = (const float*)d_in[9];
  const float* g1      = (const float*)d_in[10];
  const float* be1     = (const float*)d_in[11];
  const float* W1      = (const float*)d_in[12];
  const float* b1      = (const float*)d_in[13];
  const float* W2      = (const float*)d_in[14];
  const float* b2      = (const float*)d_in[15];
  const float* g2      = (const float*)d_in[16];
  const float* be2     = (const float*)d_in[17];
  const float* W_fc    = (const float*)d_in[18];
  const float* b_fc    = (const float*)d_in[19];
  float* out = (float*)d_out;

  // workspace: x(2MB) | qb(1MB) | kb(1MB) | vt(1MB) | ao(2MB) | packed W
  float* x = (float*)d_ws;
  unsigned int* qbw = (unsigned int*)(x + 8192 * 64);
  unsigned int* kbw = qbw + 64 * 1024 * 4;
  unsigned short* vtw = (unsigned short*)(kbw + 64 * 1024 * 4);
  float* ao = (float*)(vtw + 64 * 8 * 1024);
  unsigned int* wbo = (unsigned int*)(ao + 8192 * 64);
  unsigned int* w1b = wbo + 6144;
  unsigned int* w2b = w1b + 24576;
  unsigned int* wqb = w2b + 24576;

  k_qkv0<<<1024, 192, 0, stream>>>(weather, coords, W_emb, b_emb,
                                   W_qkv, b_qkv, gran, tidx,
                                   W_out, W1, W2,
                                   x, qbw, kbw, vtw, wbo, w1b, w2b, wqb);
  for (int l = 0; l < 3; ++l) {
    k_attn<<<1024, 512, 0, stream>>>(qbw, kbw, vtw, ao);
    if (l < 2) {
      k_fused<true, false><<<2048, 256, 0, stream>>>(
          x, ao, wbo + l * 2048, b_out + l * 64,
          g1 + l * 64, be1 + l * 64, w1b + l * 8192, b1 + l * 256,
          w2b + l * 8192, b2 + l * 64, g2 + l * 64, be2 + l * 64,
          wqb + l * 6144, b_qkv + (l + 1) * 192,
          gran + (l + 1) * 31 * 64, tidx, qbw, kbw, vtw,
          nullptr, nullptr, nullptr, x);
    } else {
      k_fused<false, true><<<2048, 256, 0, stream>>>(
          x, ao, wbo + l * 2048, b_out + l * 64,
          g1 + l * 64, be1 + l * 64, w1b + l * 8192, b1 + l * 256,
          w2b + l * 8192, b2 + l * 64, g2 + l * 64, be2 + l * 64,
          nullptr, nullptr, nullptr, nullptr, nullptr, nullptr, nullptr,
          W_fc, b_fc, out, nullptr);
    }
  }
}

// Round 26
// 157.018 us; speedup vs baseline: 1.0821x; 1.0821x over previous
//
#include <hip/hip_runtime.h>
#include <math.h>

#define EPS 1e-5f

typedef float f32x16 __attribute__((ext_vector_type(16)));
typedef short short8 __attribute__((ext_vector_type(8)));

union U4S8 { uint4 u; short8 s; };

__device__ __forceinline__ float wave_sum64(float v) {
#pragma unroll
  for (int off = 32; off >= 1; off >>= 1) v += __shfl_xor(v, off, 64);
  return v;
}

__device__ __forceinline__ unsigned int bf16rne(float f) {
  unsigned int u = __float_as_uint(f);
  return (u + 0x7fffu + ((u >> 16) & 1u)) >> 16;
}
__device__ __forceinline__ float blo(unsigned int u) {
  return __uint_as_float(u << 16);
}
__device__ __forceinline__ float bhi(unsigned int u) {
  return __uint_as_float(u & 0xffff0000u);
}
__device__ __forceinline__ unsigned int cvt_pk_bf16(float lo, float hi) {
  unsigned int r;
  asm("v_cvt_pk_bf16_f32 %0, %1, %2" : "=v"(r) : "v"(lo), "v"(hi));
  return r;
}

// K0: embed + qkv projection for layer 0 + weight prep, fused (round-24).
__global__ __launch_bounds__(192) void k_qkv0(
    const float* __restrict__ weather, const float* __restrict__ coords,
    const float* __restrict__ W_emb, const float* __restrict__ b_emb,
    const float* __restrict__ Wq, const float* __restrict__ bq,
    const float* __restrict__ gran, const int* __restrict__ tidx,
    const float* __restrict__ Wo_f, const float* __restrict__ W1_f,
    const float* __restrict__ W2_f,
    float* __restrict__ x, unsigned int* __restrict__ qb,
    unsigned int* __restrict__ kbuf, unsigned short* __restrict__ vt,
    unsigned int* __restrict__ wbo, unsigned int* __restrict__ w1b,
    unsigned int* __restrict__ w2b, unsigned int* __restrict__ wqb) {
  int t = threadIdx.x;
  int row0 = blockIdx.x << 3;
  __shared__ float wrow[8][32];
  __shared__ float xs[8][64];
  for (int i = t; i < 256; i += 192) {
    int r = i >> 5, c2 = i & 31;
    if (c2 < 31) wrow[r][c2] = weather[(size_t)(row0 + r) * 31 + c2];
  }
  __syncthreads();
  int b = row0 >> 10;
  float lat = coords[b * 2 + 0] * 0.017453292519943295f;
  float lon = coords[b * 2 + 1] * 0.017453292519943295f;
  for (int idx = t; idx < 512; idx += 192) {
    int r = idx >> 6, e = idx & 63;
    int s = (row0 + r) & 1023;
    float acc = b_emb[e];
#pragma unroll
    for (int i = 0; i < 31; ++i) acc = fmaf(wrow[r][i], W_emb[i * 64 + e], acc);
    int g = e >> 2, rem = e & 3;
    float div = __expf(-0.5756462732485115f * (float)g);
    float pe;
    if (rem == 0)      pe = sinf((float)s * div);
    else if (rem == 1) pe = cosf((float)s * div);
    else if (rem == 2) pe = sinf(lat * div);
    else               pe = cosf(lon * div);
    float xv = acc + pe;
    xs[r][e] = xv;
    x[(size_t)(row0 + r) * 64 + e] = xv;
  }
  __syncthreads();
  float acc[8];
  float bias = bq[t];
#pragma unroll
  for (int r = 0; r < 8; ++r) acc[r] = bias;
#pragma unroll 4
  for (int k4 = 0; k4 < 16; ++k4) {
    float4 xv[8];
#pragma unroll
    for (int r = 0; r < 8; ++r) xv[r] = *(const float4*)(&xs[r][4 * k4]);
    float w0 = Wq[(4 * k4 + 0) * 192 + t];
    float w1 = Wq[(4 * k4 + 1) * 192 + t];
    float w2 = Wq[(4 * k4 + 2) * 192 + t];
    float w3 = Wq[(4 * k4 + 3) * 192 + t];
#pragma unroll
    for (int r = 0; r < 8; ++r) {
      acc[r] = fmaf(xv[r].x, w0, acc[r]);
      acc[r] = fmaf(xv[r].y, w1, acc[r]);
      acc[r] = fmaf(xv[r].z, w2, acc[r]);
      acc[r] = fmaf(xv[r].w, w3, acc[r]);
    }
  }
  int cq = t & 63;
  int hh = cq >> 3, hd = t & 7;
  int shi = (row0 & 1023) >> 3;
  int s2 = (b << 7) | shi;
  const float scl = 0.35355339059327373f;
#pragma unroll
  for (int r = 0; r < 8; ++r) {
    float o = acc[r];
    if (t < 128) o += gran[tidx[2 * r + 1] * 64 + cq];
    int bh = (r << 3) | hh;
    if (t < 64) {
      o *= scl;
      float nb = __shfl_down(o, 1, 64);
      if ((hd & 1) == 0)
        qb[((((size_t)bh << 10) | s2) << 2) + (hd >> 1)] =
            bf16rne(o) | (bf16rne(nb) << 16);
    } else if (t < 128) {
      float nb = __shfl_down(o, 1, 64);
      if ((hd & 1) == 0)
        kbuf[((((size_t)bh << 10) | s2) << 2) + (hd >> 1)] =
            bf16rne(o) | (bf16rne(nb) << 16);
    } else {
      vt[((size_t)bh << 13) + (hd << 10) + s2] = (unsigned short)bf16rne(o);
    }
  }
  // ---- weight-prep phase (one packed pair per thread, gid < 67584)
  int gid = blockIdx.x * 192 + t;
  if (gid < 6144) {
    int ll = gid >> 11, rem = gid & 2047, p = rem >> 6, c2 = rem & 63;
    const float* s = Wo_f + ll * 4096;
    wbo[gid] = bf16rne(s[(2 * p) * 64 + c2]) |
               (bf16rne(s[(2 * p + 1) * 64 + c2]) << 16);
  } else if (gid < 30720) {
    int i = gid - 6144;
    int ll = i / 8192, rem = i & 8191, p = rem >> 8, c2 = rem & 255;
    const float* s = W1_f + (size_t)ll * 16384;
    w1b[i] = bf16rne(s[(2 * p) * 256 + c2]) |
             (bf16rne(s[(2 * p + 1) * 256 + c2]) << 16);
  } else if (gid < 55296) {
    int i = gid - 30720;
    int ll = i / 8192, rem = i & 8191, p = rem >> 6, c2 = rem & 63;
    const float* s = W2_f + (size_t)ll * 16384;
    w2b[i] = bf16rne(s[(2 * p) * 64 + c2]) |
             (bf16rne(s[(2 * p + 1) * 64 + c2]) << 16);
  } else if (gid < 67584) {
    int i = gid - 55296;
    int ll = i / 6144, rem = i % 6144, p = rem / 192, c2 = rem % 192;
    const float* s = Wq + (size_t)(ll + 1) * 12288;
    wqb[i] = bf16rne(s[(2 * p) * 192 + c2]) |
             (bf16rne(s[(2 * p + 1) * 192 + c2]) << 16);
  }
}

// K3 v3: MFMA flash attention, split-K x4 in-block (round-24 kernel).
__global__ __launch_bounds__(512, 2) void k_attn(
    const unsigned int* __restrict__ qb, const unsigned int* __restrict__ kbuf,
    const unsigned short* __restrict__ vt, float* __restrict__ ao) {
  int bh = blockIdx.x >> 4, chunk = blockIdx.x & 15;
  int slo = bh >> 3, h = bh & 7;
  int t = threadIdx.x;
  int l = t & 63, w = t >> 6;
  int grp = w >> 2, kh = w & 3;   // 2 q-groups x 4 key-splits
  int lq = l & 31, g = l >> 5;
  bool kl = (l < 32);
  bool vl = (lq < 8);
  int q = (chunk << 6) + (grp << 5) + lq;

  U4S8 qf;
  qf.u = make_uint4(0, 0, 0, 0);
  if (kl) qf.u = *(const uint4*)(qb + ((((size_t)bh << 10) + q) << 2));

  const uint4* kp = (const uint4*)(kbuf + ((size_t)bh << 12));
  const unsigned short* vp = vt + ((size_t)bh << 13);

  f32x16 O, Z;
#pragma unroll
  for (int i = 0; i < 16; ++i) { O[i] = 0.f; Z[i] = 0.f; }
  float m = -1e30f, ls = 0.f;

  int kb0 = kh << 3;
  for (int kblk = kb0; kblk < kb0 + 8; ++kblk) {
    U4S8 af;
    af.u = make_uint4(0, 0, 0, 0);
    if (kl) af.u = kp[(kblk << 5) + lq];
    f32x16 S = __builtin_amdgcn_mfma_f32_32x32x16_bf16(af.s, qf.s, Z, 0, 0, 0);

    float mx = S[0];
#pragma unroll
    for (int i = 1; i < 16; ++i) mx = fmaxf(mx, S[i]);
    mx = fmaxf(mx, __shfl_xor(mx, 32, 64));
    if (mx > m + 8.f) {
      float esc = __expf(m - mx);
      ls *= esc;
      O *= esc;
      m = mx;
    }
    float p[16];
#pragma unroll
    for (int i = 0; i < 16; ++i) p[i] = __expf(S[i] - m);
    float s01 = (p[0] + p[1]) + (p[2] + p[3]);
    float s23 = (p[4] + p[5]) + (p[6] + p[7]);
    float s45 = (p[8] + p[9]) + (p[10] + p[11]);
    float s67 = (p[12] + p[13]) + (p[14] + p[15]);
    ls += (s01 + s23) + (s45 + s67);

    unsigned va = cvt_pk_bf16(p[0], p[1]),  vb = cvt_pk_bf16(p[2], p[3]);
    unsigned vc = cvt_pk_bf16(p[4], p[5]),  vd = cvt_pk_bf16(p[6], p[7]);
    unsigned ve = cvt_pk_bf16(p[8], p[9]),  vf = cvt_pk_bf16(p[10], p[11]);
    unsigned vg = cvt_pk_bf16(p[12], p[13]), vh = cvt_pk_bf16(p[14], p[15]);
    unsigned sa = __shfl_xor((int)va, 32, 64), sb = __shfl_xor((int)vb, 32, 64);
    unsigned sc = __shfl_xor((int)vc, 32, 64), sd = __shfl_xor((int)vd, 32, 64);
    unsigned se = __shfl_xor((int)ve, 32, 64), sf = __shfl_xor((int)vf, 32, 64);
    unsigned sg = __shfl_xor((int)vg, 32, 64), sh = __shfl_xor((int)vh, 32, 64);
    U4S8 b1, b2;
    b1.u.x = kl ? va : sc;  b1.u.y = kl ? vb : sd;
    b1.u.z = kl ? sa : vc;  b1.u.w = kl ? sb : vd;
    b2.u.x = kl ? ve : sg;  b2.u.y = kl ? vf : sh;
    b2.u.z = kl ? se : vg;  b2.u.w = kl ? sf : vh;

    U4S8 v1, v2;
    v1.u = make_uint4(0, 0, 0, 0);
    v2.u = make_uint4(0, 0, 0, 0);
    if (vl) {
      const unsigned short* vb8 = vp + (lq << 10) + (kblk << 5) + (g << 3);
      v1.u = *(const uint4*)vb8;
      v2.u = *(const uint4*)(vb8 + 16);
    }
    O = __builtin_amdgcn_mfma_f32_32x32x16_bf16(v1.s, b1.s, O, 0, 0, 0);
    O = __builtin_amdgcn_mfma_f32_32x32x16_bf16(v2.s, b2.s, O, 0, 0, 0);
  }

  ls += __shfl_xor(ls, 32, 64);  // pair partials share m -> plain add

  // 4-way cross-wave merge (12KB LDS); wave kh==0 merges and writes.
  __shared__ float pm[2][4][64], pl[2][4][64];
  __shared__ float po[2][4][64][4];
  pm[grp][kh][l] = m;
  pl[grp][kh][l] = ls;
  *(float4*)(&po[grp][kh][l][0]) = make_float4(O[0], O[1], O[2], O[3]);
  __syncthreads();
  if (kh == 0) {
    float M = m;
#pragma unroll
    for (int j = 1; j < 4; ++j) M = fmaxf(M, pm[grp][j][l]);
    float w0 = __expf(m - M);
    float L = ls * w0;
    float o0 = O[0] * w0, o1 = O[1] * w0, o2 = O[2] * w0, o3 = O[3] * w0;
#pragma unroll
    for (int j = 1; j < 4; ++j) {
      float wj = __expf(pm[grp][j][l] - M);
      L = fmaf(pl[grp][j][l], wj, L);
      float4 oj = *(const float4*)(&po[grp][j][l][0]);
      o0 = fmaf(oj.x, wj, o0);
      o1 = fmaf(oj.y, wj, o1);
      o2 = fmaf(oj.z, wj, o2);
      o3 = fmaf(oj.w, wj, o3);
    }
    float inv = 1.0f / L;
    int bq2 = q >> 7, sq = ((q & 127) << 3) | slo;
    float* op = ao + (((size_t)((bq2 << 10) | sq)) << 6) + (h << 3) + (g << 2);
    *(float4*)op = make_float4(o0 * inv, o1 * inv, o2 * inv, o3 * inv);
  }
}

// K4 v11 (round-24 kernel): occupancy-first fused layer, 2 rows/wave,
// 8 rows/block, grid 1024, bf16-packed weights, optional next-layer qkv
// emission, optional head. (256,4) cap; VGPR ~52, no spills.
template <bool EMIT, bool HEAD>
__global__ __launch_bounds__(256, 4) void k_fused(
    const float* x_in, const float* __restrict__ ao,
    const unsigned int* __restrict__ Wo, const float* __restrict__ bo,
    const float* __restrict__ g1, const float* __restrict__ be1,
    const unsigned int* __restrict__ W1, const float* __restrict__ b1,
    const unsigned int* __restrict__ W2, const float* __restrict__ b2,
    const float* __restrict__ g2, const float* __restrict__ be2,
    const unsigned int* __restrict__ Wq, const float* __restrict__ bq,
    const float* __restrict__ gran, const int* __restrict__ tidx,
    unsigned int* __restrict__ qbo, unsigned int* __restrict__ kbo,
    unsigned short* __restrict__ vto,
    const float* __restrict__ Wfc, const float* __restrict__ bfc,
    float* __restrict__ outp, float* __restrict__ x_out) {
  int t = threadIdx.x, w = t >> 6, c = t & 63;
  int ws = w << 1;                  // 2 rows per wave
  int row_base = blockIdx.x << 3;   // 8 rows per block
  int row0 = row_base + ws;
  __shared__ float aos[8][64];      // ao -> x1 -> x_out staging
  __shared__ float h1s[8][256];
  float xin[2];
#pragma unroll
  for (int r = 0; r < 2; ++r) {
    aos[ws + r][c] = ao[(size_t)(row0 + r) * 64 + c];
    xin[r] = x_in[(size_t)(row0 + r) * 64 + c];
  }
  // ---- proj + residual + LN1 (wave-private rows; no barrier)
  float acc[2];
  float bov = bo[c];
#pragma unroll
  for (int r = 0; r < 2; ++r) acc[r] = bov;
#pragma unroll 4
  for (int k4 = 0; k4 < 16; ++k4) {
    unsigned a = Wo[(2 * k4) * 64 + c], b = Wo[(2 * k4 + 1) * 64 + c];
    float w0 = blo(a), w1 = bhi(a), w2 = blo(b), w3 = bhi(b);
#pragma unroll
    for (int r = 0; r < 2; ++r) {
      float4 av = *(const float4*)(&aos[ws + r][4 * k4]);
      acc[r] = fmaf(av.x, w0, acc[r]);
      acc[r] = fmaf(av.y, w1, acc[r]);
      acc[r] = fmaf(av.z, w2, acc[r]);
      acc[r] = fmaf(av.w, w3, acc[r]);
    }
  }
  float g1v = g1[c], be1v = be1[c];
  float x1v[2];
#pragma unroll
  for (int r = 0; r < 2; ++r) {
    float y = acc[r] + xin[r];
    float s1 = wave_sum64(y), s2 = wave_sum64(y * y);
    float mean = s1 * 0.015625f, var = s2 * 0.015625f - mean * mean;
    x1v[r] = (y - mean) * rsqrtf(var + EPS) * g1v + be1v;
    aos[ws + r][c] = x1v[r];  // aos dead after proj; reuse for x1
  }
  // ---- ffn1 (x1 from aos, wave-private; W1 bf16 pairs)
  float4 h[2];
  float4 b1v = *(const float4*)(b1 + 4 * c);
#pragma unroll
  for (int r = 0; r < 2; ++r) h[r] = b1v;
#pragma unroll 4
  for (int k4 = 0; k4 < 16; ++k4) {
    uint4 A = *(const uint4*)(W1 + (2 * k4) * 256 + 4 * c);
    uint4 B = *(const uint4*)(W1 + (2 * k4 + 1) * 256 + 4 * c);
    float4 w0 = make_float4(blo(A.x), blo(A.y), blo(A.z), blo(A.w));
    float4 w1 = make_float4(bhi(A.x), bhi(A.y), bhi(A.z), bhi(A.w));
    float4 w2 = make_float4(blo(B.x), blo(B.y), blo(B.z), blo(B.w));
    float4 w3 = make_float4(bhi(B.x), bhi(B.y), bhi(B.z), bhi(B.w));
#pragma unroll
    for (int r = 0; r < 2; ++r) {
      float4 xv = *(const float4*)(&aos[ws + r][4 * k4]);
      h[r].x = fmaf(xv.x, w0.x, h[r].x); h[r].y = fmaf(xv.x, w0.y, h[r].y);
      h[r].z = fmaf(xv.x, w0.z, h[r].z); h[r].w = fmaf(xv.x, w0.w, h[r].w);
      h[r].x = fmaf(xv.y, w1.x, h[r].x); h[r].y = fmaf(xv.y, w1.y, h[r].y);
      h[r].z = fmaf(xv.y, w1.z, h[r].z); h[r].w = fmaf(xv.y, w1.w, h[r].w);
      h[r].x = fmaf(xv.z, w2.x, h[r].x); h[r].y = fmaf(xv.z, w2.y, h[r].y);
      h[r].z = fmaf(xv.z, w2.z, h[r].z); h[r].w = fmaf(xv.z, w2.w, h[r].w);
      h[r].x = fmaf(xv.w, w3.x, h[r].x); h[r].y = fmaf(xv.w, w3.y, h[r].y);
      h[r].z = fmaf(xv.w, w3.z, h[r].z); h[r].w = fmaf(xv.w, w3.w, h[r].w);
    }
  }
#pragma unroll
  for (int r = 0; r < 2; ++r) {
    h[r].x = fmaxf(h[r].x, 0.f); h[r].y = fmaxf(h[r].y, 0.f);
    h[r].z = fmaxf(h[r].z, 0.f); h[r].w = fmaxf(h[r].w, 0.f);
    *(float4*)(&h1s[ws + r][4 * c]) = h[r];
  }
  // ---- ffn2 (h1 wave-private from LDS; W2 bf16 pairs) + LN2
  float acc2[2];
  float b2v = b2[c];
#pragma unroll
  for (int r = 0; r < 2; ++r) acc2[r] = b2v;
#pragma unroll 4
  for (int k4 = 0; k4 < 64; ++k4) {
    unsigned a = W2[(2 * k4) * 64 + c], b = W2[(2 * k4 + 1) * 64 + c];
    float w0 = blo(a), w1 = bhi(a), w2 = blo(b), w3 = bhi(b);
#pragma unroll
    for (int r = 0; r < 2; ++r) {
      float4 hv = *(const float4*)(&h1s[ws + r][4 * k4]);
      acc2[r] = fmaf(hv.x, w0, acc2[r]);
      acc2[r] = fmaf(hv.y, w1, acc2[r]);
      acc2[r] = fmaf(hv.z, w2, acc2[r]);
      acc2[r] = fmaf(hv.w, w3, acc2[r]);
    }
  }
  float g2v = g2[c], be2v = be2[c];
#pragma unroll
  for (int r = 0; r < 2; ++r) {
    float y2 = acc2[r] + x1v[r];
    float t1 = wave_sum64(y2), t2 = wave_sum64(y2 * y2);
    float mean2 = t1 * 0.015625f, var2 = t2 * 0.015625f - mean2 * mean2;
    float xo = (y2 - mean2) * rsqrtf(var2 + EPS) * g2v + be2v;
    if (!HEAD) x_out[(size_t)(row0 + r) * 64 + c] = xo;
    aos[ws + r][c] = xo;  // stage for qkv/head phase (x1 dead now)
  }
  if (EMIT) {
    __syncthreads();  // all 8 x_out rows visible block-wide
    if (t < 192) {
      float qa[8];
      float bias = bq[t];
#pragma unroll
      for (int r = 0; r < 8; ++r) qa[r] = bias;
#pragma unroll 4
      for (int k4 = 0; k4 < 16; ++k4) {
        unsigned a = Wq[(2 * k4) * 192 + t], b = Wq[(2 * k4 + 1) * 192 + t];
        float w0 = blo(a), w1 = bhi(a), w2v = blo(b), w3 = bhi(b);
#pragma unroll
        for (int r = 0; r < 8; ++r) {
          float4 av = *(const float4*)(&aos[r][4 * k4]);
          qa[r] = fmaf(av.x, w0, qa[r]);
          qa[r] = fmaf(av.y, w1, qa[r]);
          qa[r] = fmaf(av.z, w2v, qa[r]);
          qa[r] = fmaf(av.w, w3, qa[r]);
        }
      }
      int cq = t & 63, hh = cq >> 3, hd = t & 7;
      int bb = row_base >> 10;
      int s2 = (bb << 7) | ((row_base & 1023) >> 3);  // same for all 8 rows
      const float scl = 0.35355339059327373f;
#pragma unroll
      for (int r = 0; r < 8; ++r) {
        float o = qa[r];
        if (t < 128) o += gran[tidx[2 * r + 1] * 64 + cq];
        int bh = (r << 3) | hh;
        size_t base = ((size_t)(bh << 10)) | s2;
        if (t < 64) {
          o *= scl;
          float nb = __shfl_down(o, 1, 64);
          if ((hd & 1) == 0)
            qbo[(base << 2) + (hd >> 1)] = bf16rne(o) | (bf16rne(nb) << 16);
        } else if (t < 128) {
          float nb = __shfl_down(o, 1, 64);
          if ((hd & 1) == 0)
            kbo[(base << 2) + (hd >> 1)] = bf16rne(o) | (bf16rne(nb) << 16);
        } else {
          vto[((size_t)bh << 13) + (hd << 10) + s2] = (unsigned short)bf16rne(o);
        }
      }
    }
  }
  if (HEAD) {
    __syncthreads();  // all 8 x_out rows visible block-wide
    int r = t >> 5, o = t & 31;  // 8 rows x 32 slots; o==31 idle
    if (o < 31) {
      float acc3 = bfc[o];
#pragma unroll 8
      for (int i = 0; i < 64; ++i)
        acc3 = fmaf(aos[r][i], Wfc[i * 31 + o], acc3);
      outp[(size_t)(row_base + r) * 31 + o] = acc3;
    }
  }
}

extern "C" void kernel_launch(void* const* d_in, const int* in_sizes, int n_in,
                              void* d_out, int out_size, void* d_ws, size_t ws_size,
                              hipStream_t stream) {
  const float* weather = (const float*)d_in[0];
  const float* coords  = (const float*)d_in[1];
  const int*   tidx    = (const int*)d_in[2];
  const float* W_emb   = (const float*)d_in[3];
  const float* b_emb   = (const float*)d_in[4];
  const float* W_qkv   = (const float*)d_in[5];
  const float* b_qkv   = (const float*)d_in[6];
  const float* W_out   = (const float*)d_in[7];
  const float* b_out   = (const float*)d_in[8];
  const float* gran    = (const float*)d_in[9];
  const float* g1      = (const float*)d_in[10];
  const float* be1     = (const float*)d_in[11];
  const float* W1      = (const float*)d_in[12];
  const float* b1      = (const float*)d_in[13];
  const float* W2      = (const float*)d_in[14];
  const float* b2      = (const float*)d_in[15];
  const float* g2      = (const float*)d_in[16];
  const float* be2     = (const float*)d_in[17];
  const float* W_fc    = (const float*)d_in[18];
  const float* b_fc    = (const float*)d_in[19];
  float* out = (float*)d_out;

  // workspace: x(2MB) | qb(1MB) | kb(1MB) | vt(1MB) | ao(2MB) | packed W
  float* x = (float*)d_ws;
  unsigned int* qbw = (unsigned int*)(x + 8192 * 64);
  unsigned int* kbw = qbw + 64 * 1024 * 4;
  unsigned short* vtw = (unsigned short*)(kbw + 64 * 1024 * 4);
  float* ao = (float*)(vtw + 64 * 8 * 1024);
  unsigned int* wbo = (unsigned int*)(ao + 8192 * 64);
  unsigned int* w1b = wbo + 6144;
  unsigned int* w2b = w1b + 24576;
  unsigned int* wqb = w2b + 24576;

  k_qkv0<<<1024, 192, 0, stream>>>(weather, coords, W_emb, b_emb,
                                   W_qkv, b_qkv, gran, tidx,
                                   W_out, W1, W2,
                                   x, qbw, kbw, vtw, wbo, w1b, w2b, wqb);
  for (int l = 0; l < 3; ++l) {
    k_attn<<<1024, 512, 0, stream>>>(qbw, kbw, vtw, ao);
    if (l < 2) {
      k_fused<true, false><<<1024, 256, 0, stream>>>(
          x, ao, wbo + l * 2048, b_out + l * 64,
          g1 + l * 64, be1 + l * 64, w1b + l * 8192, b1 + l * 256,
          w2b + l * 8192, b2 + l * 64, g2 + l * 64, be2 + l * 64,
          wqb + l * 6144, b_qkv + (l + 1) * 192,
          gran + (l + 1) * 31 * 64, tidx, qbw, kbw, vtw,
          nullptr, nullptr, nullptr, x);
    } else {
      k_fused<false, true><<<1024, 256, 0, stream>>>(
          x, ao, wbo + l * 2048, b_out + l * 64,
          g1 + l * 64, be1 + l * 64, w1b + l * 8192, b1 + l * 256,
          w2b + l * 8192, b2 + l * 64, g2 + l * 64, be2 + l * 64,
          nullptr, nullptr, nullptr, nullptr, nullptr, nullptr, nullptr,
          W_fc, b_fc, out, nullptr);
    }
  }
}